// Round 11
// baseline (728.336 us; speedup 1.0000x reference)
//
#include <hip/hip_runtime.h>
#include <stdint.h>

// Axial attention (H axis), N=8 H=128 W=128 C=512, GROUPS=8, gp=64.
// Pipeline: wconv -> xconv(bf16+permute) -> QKV GEMM -> FUSED attn+outproj.
// R11: k_fused rebuilt on T14 reg-staging (issue-early/write-late). No global_load_lds,
// no manual vmcnt in k_fused — all global-load waits are compiler register deps.
// Q/K(g+1),V(g+1) issued pre-B2 (pinned by asm memory clobbers), ds-written post-B4:
// issue-to-use spans softmax+PV. Outproj: w4a/w4b double reg-buffer, unroll-2 static.

typedef __attribute__((ext_vector_type(4))) float f32x4;
typedef __attribute__((ext_vector_type(8))) short bf16x8;
typedef unsigned short u16;
typedef unsigned int u32;

#define CBAR() asm volatile("" ::: "memory")
#define SBAR() do { CBAR(); __builtin_amdgcn_s_barrier(); CBAR(); } while(0)
#define LGKM0() do { asm volatile("s_waitcnt lgkmcnt(0)" ::: "memory"); __builtin_amdgcn_sched_barrier(0); } while(0)
#define LGKMW() asm volatile("s_waitcnt lgkmcnt(0)" ::: "memory")
#define VMC(n) asm volatile("s_waitcnt vmcnt(" #n ")" ::: "memory")

static __device__ __forceinline__ u16 f2bf(float f){
    union { float f; u32 u; } v; v.f = f;
    u32 r = v.u + 0x7fffu + ((v.u >> 16) & 1u);   // RNE
    return (u16)(r >> 16);
}

static __device__ __forceinline__ void gload16(const void* g, void* l){
    __builtin_amdgcn_global_load_lds((const __attribute__((address_space(1))) void*)g,
                                     (__attribute__((address_space(3))) void*)l, 16, 0, 0);
}

// ---------------- weights fp32 -> bf16 ----------------
__global__ void k_wconv(const float* __restrict__ Wq, const float* __restrict__ Wk,
                        const float* __restrict__ Wv, const float* __restrict__ Wo,
                        u16* __restrict__ Wcat, u16* __restrict__ Wob){
    int e = (blockIdx.x * 256 + threadIdx.x) * 4;
    if (e < 1536*512) {
        int row = e >> 9, col = e & 511;
        const float* s = (row < 512) ? (Wq + row*512)
                        : (row < 1024 ? Wk + (row-512)*512 : Wv + (row-1024)*512);
        float4 v = *(const float4*)(s + col);
        ushort4 o = { f2bf(v.x), f2bf(v.y), f2bf(v.z), f2bf(v.w) };
        *(ushort4*)(Wcat + e) = o;
    } else {
        int e2 = e - 1536*512;
        float4 v = *(const float4*)(Wo + e2);
        ushort4 o = { f2bf(v.x), f2bf(v.y), f2bf(v.z), f2bf(v.w) };
        *(ushort4*)(Wob + e2) = o;
    }
}

// ---------------- x fp32 (N,H,W,C) -> xb bf16 [(n0+nl)*128+h][512] ----------------
__global__ void k_xconv(const float* __restrict__ x, u16* __restrict__ xb, int n0){
    int t = blockIdx.x * 256 + threadIdx.x;
    int ml = t >> 6;
    int c0 = (t & 63) << 3;
    int nl = ml >> 7, h = ml & 127;
    int n = n0 + nl, nb = n >> 7, w = n & 127;
    const float* src = x + (size_t)((nb*128 + h)*128 + w) * 512 + c0;
    float4 a = *(const float4*)(src);
    float4 b = *(const float4*)(src + 4);
    uint4 o;
    o.x = (u32)f2bf(a.x) | ((u32)f2bf(a.y) << 16);
    o.y = (u32)f2bf(a.z) | ((u32)f2bf(a.w) << 16);
    o.z = (u32)f2bf(b.x) | ((u32)f2bf(b.y) << 16);
    o.w = (u32)f2bf(b.z) | ((u32)f2bf(b.w) << 16);
    *(uint4*)(xb + (size_t)ml*512 + c0) = o;
}

// ---------------- 256x256 QKV GEMM (R7/R8 structure, frozen) ----------------
template<int NCOL>
__global__ __launch_bounds__(512, 2) void k_gemm4(const u16* __restrict__ A, const u16* __restrict__ B,
                                                  u16* __restrict__ Cout, int nrow, int planesz){
    extern __shared__ char smc[];
    const int tid = threadIdx.x;
    const int wid = tid >> 6, lane = tid & 63, lg = lane >> 4, li = lane & 15;
    const int wm = wid >> 2, wn = wid & 3;
    const int bid = blockIdx.x;
    const int xcd = bid & 7, l = bid >> 3;
    const int row_tile = xcd * (nrow >> 3) + l / NCOL;
    const int col_tile = l % NCOL;
    const int m0 = row_tile * 256, nn0 = col_tile * 256;

    const char* baseA[2]; const char* baseB[2]; int dstR[2];
    #pragma unroll
    for (int i = 0; i < 2; ++i) {
        int R = wid*32 + i*16;
        int r = R + (lane >> 2);
        int cq = (lane & 3) ^ ((r >> 1) & 3);
        baseA[i] = (const char*)(A + (size_t)(m0 + r)*512) + cq*16;
        baseB[i] = (const char*)(B + (size_t)(nn0 + r)*512) + cq*16;
        dstR[i] = R;
    }
    auto stageA = [&](int st){
        char* sl = smc + (st & 3)*32768;
        #pragma unroll
        for (int i = 0; i < 2; ++i) gload16(baseA[i] + st*64, sl + dstR[i]*64);
    };
    auto stageB = [&](int st){
        char* sl = smc + (st & 3)*32768 + 16384;
        #pragma unroll
        for (int i = 0; i < 2; ++i) gload16(baseB[i] + st*64, sl + dstR[i]*64);
    };

    f32x4 acc[8][4];
    #pragma unroll
    for (int i = 0; i < 8; ++i)
        #pragma unroll
        for (int j = 0; j < 4; ++j)
            acc[i][j] = f32x4{0.f, 0.f, 0.f, 0.f};

    stageA(0); stageB(0);
    stageA(1); stageB(1);
    stageA(2); stageB(2);
    VMC(8);
    SBAR();

    bf16x8 af[4], bfr[4];
    for (int t = 0; t < 16; ++t) {
        char* sl = smc + (t & 3)*32768;
        #pragma unroll
        for (int f = 0; f < 4; ++f) {
            int ra = wm*128 + f*16 + li;
            af[f] = *(const bf16x8*)(sl + ra*64 + (((lg ^ (ra >> 1)) & 3) << 4));
        }
        #pragma unroll
        for (int f = 0; f < 4; ++f) {
            int rb = wn*64 + f*16 + li;
            bfr[f] = *(const bf16x8*)(sl + 16384 + rb*64 + (((lg ^ (rb >> 1)) & 3) << 4));
        }
        if (t < 13) stageA(t + 3);
        SBAR(); LGKM0();
        __builtin_amdgcn_s_setprio(1);
        #pragma unroll
        for (int fi = 0; fi < 4; ++fi)
            #pragma unroll
            for (int fj = 0; fj < 4; ++fj)
                acc[fi][fj] = __builtin_amdgcn_mfma_f32_16x16x32_bf16(af[fi], bfr[fj], acc[fi][fj], 0, 0, 0);
        __builtin_amdgcn_s_setprio(0);
        SBAR();
        #pragma unroll
        for (int f = 0; f < 4; ++f) {
            int ra = wm*128 + (4 + f)*16 + li;
            af[f] = *(const bf16x8*)(sl + ra*64 + (((lg ^ (ra >> 1)) & 3) << 4));
        }
        if (t < 13) stageB(t + 3);
        SBAR(); LGKM0();
        __builtin_amdgcn_s_setprio(1);
        #pragma unroll
        for (int fi = 0; fi < 4; ++fi)
            #pragma unroll
            for (int fj = 0; fj < 4; ++fj)
                acc[4 + fi][fj] = __builtin_amdgcn_mfma_f32_16x16x32_bf16(af[fi], bfr[fj], acc[4 + fi][fj], 0, 0, 0);
        __builtin_amdgcn_s_setprio(0);
        if (t < 13)      { VMC(8); }
        else if (t == 13){ VMC(4); }
        else if (t == 14){ VMC(0); }
        SBAR();
    }

    u16* Cp = Cout + (size_t)(nn0 >> 9) * planesz;
    const int cb = (nn0 & 511) + wn*64;
    #pragma unroll
    for (int mf = 0; mf < 8; ++mf)
        #pragma unroll
        for (int nf = 0; nf < 4; ++nf)
            #pragma unroll
            for (int r = 0; r < 4; ++r) {
                int row = m0 + wm*128 + mf*16 + lg*4 + r;
                int col = cb + nf*16 + li;
                Cp[(size_t)row*512 + col] = f2bf(acc[mf][nf][r]);
            }
}

// ---------------- fused attention + outproj (T14 reg-staged) ----------------
// LDS (160KB): O region [0,128K) = 8 slots x 16KB; slot g: o(i,c)=g*16K + i*128
//   + ((c*2)^((i&7)<<4)). During group g, slot g holds Vt: vt(c,j)=g*16K + c*256
//   + ((j*2)^((c&7)<<4)) — freed by PV before the O-write.
// Scratch [128K,160K): QB(16K)+KB(16K); P overlays post-B2; outproj Bs overlays per kc.
// Per group: {QK^T; V(g) scatter; issue V/QK(g+1)->regs} B2 {softmax->P} LGKM,B3
// {PV} B4 {ds_write QK(g+1); O-write} LGKM,B1'. Global-load waits: compiler reg deps.
__global__ __launch_bounds__(512, 2) void k_fused(const u16* __restrict__ Qpl, const u16* __restrict__ Kpl,
                                                  const u16* __restrict__ Vpl, const u16* __restrict__ Wob,
                                                  const float* __restrict__ bias, float* __restrict__ out,
                                                  int n0, int cnd8){
    extern __shared__ char sm[];
    const int tid = threadIdx.x;
    const int wv = tid >> 6, lane = tid & 63, lg = lane >> 4, li = lane & 15;
    const int bid = blockIdx.x;
    const int nlL = (bid & 7)*cnd8 + (bid >> 3);
    const int n = n0 + nlL, nb = n >> 7, w = n & 127;

    char* const QB = sm + 131072;
    char* const KB = sm + 131072 + 16384;
    char* const PB = sm + 131072 + wv*4096;
    char* const SB = sm + 131072;

    const int vj = tid & 127, vch = tid >> 7;          // V loader role
    const size_t rowbase = (size_t)nlL * 128;

    // Q/K reg-stage mapping: rows i0 = tid>>3, i1 = 64 + tid>>3; chunk qc = tid&7 (16B).
    // LDS slot = qc ^ (i&7)  (same involution as the former pre-swizzled-source gload16).
    const int qi = tid >> 3, qc = tid & 7;
    const u16* const Qsrc = Qpl + rowbase*512 + (size_t)qi*512 + qc*8;
    const u16* const Ksrc = Kpl + rowbase*512 + (size_t)qi*512 + qc*8;
    const int qdst = qi*128 + ((qc ^ (qi & 7)) << 4);   // (i&7) == (qi&7) for both halves

    uint4 rq0, rq1, rk0, rk1, va, vb;
    auto issueQK = [&](int g){
        rq0 = *(const uint4*)(Qsrc + g*64);
        rq1 = *(const uint4*)(Qsrc + 64*512 + g*64);
        rk0 = *(const uint4*)(Ksrc + g*64);
        rk1 = *(const uint4*)(Ksrc + 64*512 + g*64);
    };
    auto writeQK = [&](){
        *(uint4*)(QB + qdst)        = rq0;
        *(uint4*)(QB + 8192 + qdst) = rq1;
        *(uint4*)(KB + qdst)        = rk0;
        *(uint4*)(KB + 8192 + qdst) = rk1;
    };
    auto issueV = [&](int g){
        const u16* src = Vpl + (rowbase + vj)*512 + g*64 + vch*16;
        va = *(const uint4*)(src);
        vb = *(const uint4*)(src + 8);
    };

    // prologue: group 0
    issueQK(0); issueV(0);
    writeQK();                     // compiler waits vmcnt on rq/rk deps
    LGKMW();
    SBAR();                        // B1(0)

    for (int g = 0; g < 8; ++g) {
        char* OG = sm + g*16384;

        // ---- QK^T: S[16 rows/wave][128 j]
        f32x4 s8[8];
        #pragma unroll
        for (int tj = 0; tj < 8; ++tj) s8[tj] = f32x4{0.f,0.f,0.f,0.f};
        #pragma unroll
        for (int ks = 0; ks < 2; ++ks) {
            int i = wv*16 + li;
            bf16x8 qf = *(const bf16x8*)(QB + i*128 + ((ks*64 + lg*16) ^ ((li & 7) << 4)));
            #pragma unroll
            for (int tj = 0; tj < 8; ++tj) {
                int j = tj*16 + li;
                bf16x8 kf = *(const bf16x8*)(KB + j*128 + ((ks*64 + lg*16) ^ ((li & 7) << 4)));
                s8[tj] = __builtin_amdgcn_mfma_f32_16x16x32_bf16(qf, kf, s8[tj], 0, 0, 0);
            }
        }

        // ---- V(g) scatter into slot g (Vt); then issue next-group loads (WAR on va/vb)
        {
            u32 wd[8] = {va.x, va.y, va.z, va.w, vb.x, vb.y, vb.z, vb.w};
            #pragma unroll
            for (int cc = 0; cc < 16; ++cc) {
                int c = vch*16 + cc;
                u16 val = (cc & 1) ? (u16)(wd[cc >> 1] >> 16) : (u16)(wd[cc >> 1] & 0xffffu);
                *(u16*)(OG + c*256 + ((vj*2) ^ ((c & 7) << 4))) = val;
            }
        }
        if (g < 7) { issueV(g + 1); issueQK(g + 1); }   // pinned pre-B2 by CBAR; used post-B4

        SBAR();            // B2: QK^T reads done -> P overlay legal

        // ---- softmax (scale 1/8) + P write (own wave's 4KB)
        #pragma unroll
        for (int r = 0; r < 4; ++r) {
            int ir = lg*4 + r;
            float mx = -1e30f;
            #pragma unroll
            for (int tj = 0; tj < 8; ++tj) mx = fmaxf(mx, s8[tj][r]);
            #pragma unroll
            for (int off = 1; off < 16; off <<= 1) mx = fmaxf(mx, __shfl_xor(mx, off, 64));
            float p[8]; float sum = 0.f;
            #pragma unroll
            for (int tj = 0; tj < 8; ++tj) { p[tj] = __expf((s8[tj][r] - mx)*0.125f); sum += p[tj]; }
            #pragma unroll
            for (int off = 1; off < 16; off <<= 1) sum += __shfl_xor(sum, off, 64);
            float inv = 1.0f / sum;
            #pragma unroll
            for (int tj = 0; tj < 8; ++tj) {
                int j = tj*16 + li;
                *(u16*)(PB + ir*256 + ((j*2) ^ ((ir & 7) << 4))) = f2bf(p[tj]*inv);
            }
        }

        LGKMW();
        SBAR();            // B3: P + Vt visible

        // ---- PV: O rows 16/wave x 64 c
        f32x4 o4[4];
        #pragma unroll
        for (int tc = 0; tc < 4; ++tc) o4[tc] = f32x4{0.f,0.f,0.f,0.f};
        #pragma unroll
        for (int ks = 0; ks < 4; ++ks) {
            bf16x8 pf = *(const bf16x8*)(PB + li*256 + ((ks*64 + lg*16) ^ ((li & 7) << 4)));
            #pragma unroll
            for (int tc = 0; tc < 4; ++tc) {
                int c = tc*16 + li;
                bf16x8 vf = *(const bf16x8*)(OG + c*256 + ((ks*64 + lg*16) ^ ((c & 7) << 4)));
                o4[tc] = __builtin_amdgcn_mfma_f32_16x16x32_bf16(pf, vf, o4[tc], 0, 0, 0);
            }
        }

        SBAR();            // B4: P/Vt reads done -> QB/KB + slot g reusable

        if (g < 7) writeQK();          // Q/K(g+1) -> LDS (auto vmcnt on reg deps)

        // ---- O_g -> slot g (overwrites Vt)
        #pragma unroll
        for (int tc = 0; tc < 4; ++tc)
            #pragma unroll
            for (int r = 0; r < 4; ++r) {
                int i = wv*16 + lg*4 + r;
                int c = tc*16 + li;
                *(u16*)(OG + i*128 + ((c*2) ^ ((i & 7) << 4))) = f2bf(o4[tc][r]);
            }

        LGKMW();
        SBAR();            // B1(g+1); after g=7: all O visible for outproj
    }

    // ================= outproj: Y[128x512] = O_lds * Wob^T + bias =================
    // T14 double reg-buffer w4a/w4b, unroll-2 (static indexing). SB overlays scratch.
    const int oco = tid >> 2, och = tid & 3;
    uint4 w4a[4], w4b[4];
    auto issueW = [&](uint4* W, int kc){
        #pragma unroll
        for (int p = 0; p < 4; ++p)
            W[p] = *(const uint4*)(Wob + (size_t)(p*128 + oco)*512 + kc*32 + och*8);
    };
    auto writeW = [&](const uint4* W){
        #pragma unroll
        for (int p = 0; p < 4; ++p) {
            int co = p*128 + oco;
            *(uint4*)(SB + p*8192 + oco*64 + ((och ^ ((co >> 1) & 3)) << 4)) = W[p];
        }
    };

    f32x4 y[32];
    #pragma unroll
    for (int cf = 0; cf < 32; ++cf) y[cf] = f32x4{0.f,0.f,0.f,0.f};

    auto mfmaW = [&](int kc){
        int i = wv*16 + li;
        bf16x8 af = *(const bf16x8*)(sm + (kc >> 1)*16384 + i*128 +
                                     (((kc & 1)*64 + lg*16) ^ ((li & 7) << 4)));
        __builtin_amdgcn_s_setprio(1);
        #pragma unroll
        for (int cf = 0; cf < 32; ++cf) {
            int co = cf*16 + li;
            bf16x8 bf = *(const bf16x8*)(SB + co*64 + ((lg << 4) ^ (((co >> 1) & 3) << 4)));
            y[cf] = __builtin_amdgcn_mfma_f32_16x16x32_bf16(af, bf, y[cf], 0, 0, 0);
        }
        __builtin_amdgcn_s_setprio(0);
    };

    issueW(w4a, 0);
    for (int kc2 = 0; kc2 < 16; kc2 += 2) {
        // even kc
        writeW(w4a);                       // auto vmcnt on w4a deps
        issueW(w4b, kc2 + 1);
        LGKMW(); SBAR();
        mfmaW(kc2);
        SBAR();                            // SB reads done
        // odd kc
        writeW(w4b);
        if (kc2 + 2 < 16) issueW(w4a, kc2 + 2);
        LGKMW(); SBAR();
        mfmaW(kc2 + 1);
        SBAR();
    }

    // epilogue: Y -> out (NHWC), rows = (nb*128 + i)*128 + w
    #pragma unroll
    for (int cf = 0; cf < 32; ++cf) {
        float bv = bias[cf*16 + li];
        #pragma unroll
        for (int r = 0; r < 4; ++r) {
            int i = wv*16 + lg*4 + r;
            out[((size_t)(nb*128 + i)*128 + w)*512 + cf*16 + li] = y[cf][r] + bv;
        }
    }
}

extern "C" void kernel_launch(void* const* d_in, const int* in_sizes, int n_in,
                              void* d_out, int out_size, void* d_ws, size_t ws_size,
                              hipStream_t stream){
    const float* x  = (const float*)d_in[0];
    const float* Wq = (const float*)d_in[1];
    const float* Wk = (const float*)d_in[2];
    const float* Wv = (const float*)d_in[3];
    const float* Wo = (const float*)d_in[4];
    const float* bo = (const float*)d_in[5];

    char* ws = (char*)d_ws;
    u16* Wcat = (u16*)ws;               // 1536*512 bf16
    u16* Wob  = Wcat + 1536*512;        // 512*512 bf16 ; weights end at 2097152 B

    int CN = 1024;
    while (CN > 128 && (size_t)2097152 + (size_t)CN*524288 > ws_size) CN >>= 1;
    u16* xb   = (u16*)(ws + 2097152);
    u16* QKV2 = xb + (size_t)CN*128*512;   // 3 planes [CN*128][512]
    int planesz = CN*128*512;

    hipFuncSetAttribute((const void*)&k_gemm4<6>,
                        hipFuncAttributeMaxDynamicSharedMemorySize, 131072);
    hipFuncSetAttribute((const void*)&k_fused,
                        hipFuncAttributeMaxDynamicSharedMemorySize, 163840);

    k_wconv<<<1024, 256, 0, stream>>>(Wq, Wk, Wv, Wo, Wcat, Wob);
    int nch = 1024 / CN;
    for (int ch = 0; ch < nch; ++ch) {
        int n0 = ch * CN;
        int nrow = (CN * 128) / 256;
        k_xconv<<<CN*32, 256, 0, stream>>>(x, xb, n0);
        k_gemm4<6><<<nrow*6, 512, 131072, stream>>>(xb, Wcat, QKV2, nrow, planesz);
        k_fused<<<CN, 512, 163840, stream>>>(QKV2, QKV2 + planesz, QKV2 + 2*(size_t)planesz,
                                             Wob, bo, (float*)d_out, n0, CN/8);
    }
}

// Round 12
// 614.343 us; speedup vs baseline: 1.1856x; 1.1856x over previous
//
#include <hip/hip_runtime.h>
#include <stdint.h>

// Axial attention (H axis), N=8 H=128 W=128 C=512, GROUPS=8, gp=64.
// Pipeline (R8 structure — session best 615us — with attn occupancy 2->3):
// wconv -> xconv(bf16+permute) -> QKV GEMM -> attn -> outproj.
// GEMM (k_gemm4): 256x256 block, 8 waves (2x4, wave-out 128x64), BK=32 K-steps,
// 4 rotating 32KB buffers (128 KiB LDS), depth-3 prefetch, counted vmcnt(8),
// slot-XOR swizzle (R6-verified conflicts=0).
// OUTPROJ tile remap (R8): M-rows = (fixed nb, h-pair) x w[0..128) -> dense NHWC writes.
// R12: k_attn __launch_bounds__(256,3) — 3 blocks/CU (156KB LDS fits), cross-block
// overlap hides the per-phase barrier/drain stalls (attn is latency-bound).
// ws: Q/K/V as separate [M][512] planes; O overwrites xb ([M][512]).

typedef __attribute__((ext_vector_type(4))) float f32x4;
typedef __attribute__((ext_vector_type(8))) short bf16x8;
typedef unsigned short u16;
typedef unsigned int u32;

#define CBAR() asm volatile("" ::: "memory")
#define SBAR() do { CBAR(); __builtin_amdgcn_s_barrier(); CBAR(); } while(0)
#define LGKM0() do { asm volatile("s_waitcnt lgkmcnt(0)" ::: "memory"); __builtin_amdgcn_sched_barrier(0); } while(0)
#define VMC(n) asm volatile("s_waitcnt vmcnt(" #n ")" ::: "memory")

static __device__ __forceinline__ u16 f2bf(float f){
    union { float f; u32 u; } v; v.f = f;
    u32 r = v.u + 0x7fffu + ((v.u >> 16) & 1u);   // RNE
    return (u16)(r >> 16);
}

static __device__ __forceinline__ void gload16(const void* g, void* l){
    __builtin_amdgcn_global_load_lds((const __attribute__((address_space(1))) void*)g,
                                     (__attribute__((address_space(3))) void*)l, 16, 0, 0);
}

// ---------------- weights fp32 -> bf16 ----------------
__global__ void k_wconv(const float* __restrict__ Wq, const float* __restrict__ Wk,
                        const float* __restrict__ Wv, const float* __restrict__ Wo,
                        u16* __restrict__ Wcat, u16* __restrict__ Wob){
    int e = (blockIdx.x * 256 + threadIdx.x) * 4;
    if (e < 1536*512) {
        int row = e >> 9, col = e & 511;
        const float* s = (row < 512) ? (Wq + row*512)
                        : (row < 1024 ? Wk + (row-512)*512 : Wv + (row-1024)*512);
        float4 v = *(const float4*)(s + col);
        ushort4 o = { f2bf(v.x), f2bf(v.y), f2bf(v.z), f2bf(v.w) };
        *(ushort4*)(Wcat + e) = o;
    } else {
        int e2 = e - 1536*512;
        float4 v = *(const float4*)(Wo + e2);
        ushort4 o = { f2bf(v.x), f2bf(v.y), f2bf(v.z), f2bf(v.w) };
        *(ushort4*)(Wob + e2) = o;
    }
}

// ---------------- x fp32 (N,H,W,C) -> xb bf16 [(n0+nl)*128+h][512] ----------------
__global__ void k_xconv(const float* __restrict__ x, u16* __restrict__ xb, int n0){
    int t = blockIdx.x * 256 + threadIdx.x;
    int ml = t >> 6;
    int c0 = (t & 63) << 3;
    int nl = ml >> 7, h = ml & 127;
    int n = n0 + nl, nb = n >> 7, w = n & 127;
    const float* src = x + (size_t)((nb*128 + h)*128 + w) * 512 + c0;
    float4 a = *(const float4*)(src);
    float4 b = *(const float4*)(src + 4);
    uint4 o;
    o.x = (u32)f2bf(a.x) | ((u32)f2bf(a.y) << 16);
    o.y = (u32)f2bf(a.z) | ((u32)f2bf(a.w) << 16);
    o.z = (u32)f2bf(b.x) | ((u32)f2bf(b.y) << 16);
    o.w = (u32)f2bf(b.z) | ((u32)f2bf(b.w) << 16);
    *(uint4*)(xb + (size_t)ml*512 + c0) = o;
}

// ---------------- 256x256 GEMM, 4-buffer depth-3 pipeline: C = A[Mx512] * B^T ----------------
// Buf b (32KB) = A slab [256 rows][64B] + B slab [256 rows][64B] (one BK=32 K-window).
// Swizzle: LDS 16B-slot q of row r holds global chunk q^((r>>1)&3); read at lg^((r>>1)&3).
// Step t: p0 {frags A0-3+B0-3; stageA(t+3); bar; lgkm0; 16 MFMA; bar}
//         p1 {frags A4-7;      stageB(t+3); bar; lgkm0; 16 MFMA; vmcnt(8); bar}
// OUTPROJ: tile-row rho -> (w = rho&127, hh = rho>>7); A row = (nbL*128+w)*128 + h0+hh;
//          out row = (nbG*128 + h0+hh)*128 + w  (dense 2KB-stride writes).
template<int NCOL, bool OUTPROJ>
__global__ __launch_bounds__(512, 2) void k_gemm4(const u16* __restrict__ A, const u16* __restrict__ B,
                                                  void* __restrict__ Cout, const float* __restrict__ bias,
                                                  int n0, int nrow, int planesz){
    extern __shared__ char smc[];
    const int tid = threadIdx.x;
    const int wid = tid >> 6, lane = tid & 63, lg = lane >> 4, li = lane & 15;
    const int wm = wid >> 2, wn = wid & 3;           // 2 x 4 wave grid, wave out 128x64
    const int bid = blockIdx.x;
    const int xcd = bid & 7, l = bid >> 3;
    const int row_tile = xcd * (nrow >> 3) + l / NCOL;
    const int col_tile = l % NCOL;
    const int m0 = row_tile * 256, nn0 = col_tile * 256;
    const int nbL = row_tile >> 6, h0 = (row_tile & 63) * 2;   // OUTPROJ geometry

    const char* baseA[2]; const char* baseB[2]; int dstR[2];
    #pragma unroll
    for (int i = 0; i < 2; ++i) {
        int R = wid*32 + i*16;
        int r = R + (lane >> 2);
        int cq = (lane & 3) ^ ((r >> 1) & 3);
        long arow;
        if (OUTPROJ) arow = ((long)nbL*128 + (r & 127))*128 + h0 + (r >> 7);
        else         arow = m0 + r;
        baseA[i] = (const char*)(A + (size_t)arow*512) + cq*16;
        baseB[i] = (const char*)(B + (size_t)(nn0 + r)*512) + cq*16;
        dstR[i] = R;
    }
    auto stageA = [&](int st){
        char* sl = smc + (st & 3)*32768;
        #pragma unroll
        for (int i = 0; i < 2; ++i)
            gload16(baseA[i] + st*64, sl + dstR[i]*64);
    };
    auto stageB = [&](int st){
        char* sl = smc + (st & 3)*32768 + 16384;
        #pragma unroll
        for (int i = 0; i < 2; ++i)
            gload16(baseB[i] + st*64, sl + dstR[i]*64);
    };

    f32x4 acc[8][4];
    #pragma unroll
    for (int i = 0; i < 8; ++i)
        #pragma unroll
        for (int j = 0; j < 4; ++j)
            acc[i][j] = f32x4{0.f, 0.f, 0.f, 0.f};

    stageA(0); stageB(0);
    stageA(1); stageB(1);
    stageA(2); stageB(2);
    VMC(8);
    SBAR();

    bf16x8 af[4], bfr[4];
    for (int t = 0; t < 16; ++t) {
        char* sl = smc + (t & 3)*32768;

        #pragma unroll
        for (int f = 0; f < 4; ++f) {
            int ra = wm*128 + f*16 + li;
            af[f] = *(const bf16x8*)(sl + ra*64 + (((lg ^ (ra >> 1)) & 3) << 4));
        }
        #pragma unroll
        for (int f = 0; f < 4; ++f) {
            int rb = wn*64 + f*16 + li;
            bfr[f] = *(const bf16x8*)(sl + 16384 + rb*64 + (((lg ^ (rb >> 1)) & 3) << 4));
        }
        if (t < 13) stageA(t + 3);
        SBAR(); LGKM0();
        __builtin_amdgcn_s_setprio(1);
        #pragma unroll
        for (int fi = 0; fi < 4; ++fi)
            #pragma unroll
            for (int fj = 0; fj < 4; ++fj)
                acc[fi][fj] = __builtin_amdgcn_mfma_f32_16x16x32_bf16(af[fi], bfr[fj], acc[fi][fj], 0, 0, 0);
        __builtin_amdgcn_s_setprio(0);
        SBAR();

        #pragma unroll
        for (int f = 0; f < 4; ++f) {
            int ra = wm*128 + (4 + f)*16 + li;
            af[f] = *(const bf16x8*)(sl + ra*64 + (((lg ^ (ra >> 1)) & 3) << 4));
        }
        if (t < 13) stageB(t + 3);
        SBAR(); LGKM0();
        __builtin_amdgcn_s_setprio(1);
        #pragma unroll
        for (int fi = 0; fi < 4; ++fi)
            #pragma unroll
            for (int fj = 0; fj < 4; ++fj)
                acc[4 + fi][fj] = __builtin_amdgcn_mfma_f32_16x16x32_bf16(af[fi], bfr[fj], acc[4 + fi][fj], 0, 0, 0);
        __builtin_amdgcn_s_setprio(0);
        if (t < 13)      { VMC(8); }
        else if (t == 13){ VMC(4); }
        else if (t == 14){ VMC(0); }
        SBAR();
    }

    if (!OUTPROJ) {
        u16* Cp = (u16*)Cout + (size_t)(nn0 >> 9) * planesz;
        const int cb = (nn0 & 511) + wn*64;
        #pragma unroll
        for (int mf = 0; mf < 8; ++mf)
            #pragma unroll
            for (int nf = 0; nf < 4; ++nf)
                #pragma unroll
                for (int r = 0; r < 4; ++r) {
                    int row = m0 + wm*128 + mf*16 + lg*4 + r;
                    int col = cb + nf*16 + li;
                    Cp[(size_t)row*512 + col] = f2bf(acc[mf][nf][r]);
                }
    } else {
        float* C = (float*)Cout;
        const int nbG = (n0 >> 7) + nbL;
        #pragma unroll
        for (int mf = 0; mf < 8; ++mf)
            #pragma unroll
            for (int nf = 0; nf < 4; ++nf)
                #pragma unroll
                for (int r = 0; r < 4; ++r) {
                    int rho = wm*128 + mf*16 + lg*4 + r;
                    int w = rho & 127, hh = rho >> 7;
                    int col = nn0 + wn*64 + nf*16 + li;
                    size_t orow = (size_t)(nbG*128 + h0 + hh)*128 + w;
                    C[orow*512 + col] = acc[mf][nf][r] + bias[col];
                }
    }
}

// ---------------- attention: one block per (n_local, group), 4 waves x 32 rows ----------------
// R12: 3 blocks/CU (LDS 3x52224=156672 <= 160K; VGPR budget 170 at 3 waves/SIMD).
__global__ __launch_bounds__(256, 3) void k_attn(const u16* __restrict__ Qpl, const u16* __restrict__ Kpl,
                                                 const u16* __restrict__ Vpl, u16* __restrict__ Ob){
    // LDS: [0,16K) Qs swz, [16K,32K) Ks swz; P overlays [0,34816) after S-phase;
    //      Vt [34816, 34816+17408): [c=64][stride 272B] bf16
    __shared__ char sm[52224];
    const int g = blockIdx.x;
    const int nl = blockIdx.y;
    const int tid = threadIdx.x;
    const int wid = tid >> 6, lane = tid & 63, lg = lane >> 4, li = lane & 15;

    const u16* Qg = Qpl + (size_t)nl*128*512 + g*64;
    const u16* Kg = Kpl + (size_t)nl*128*512 + g*64;
    const u16* Vg = Vpl + (size_t)nl*128*512 + g*64;
    u16*       Og = Ob  + (size_t)nl*128*512 + g*64;

    #pragma unroll
    for (int it = 0; it < 4; ++it) {
        int gi = it*256 + tid;
        int row = gi >> 3, gs = gi & 7;
        int sw = (gs ^ (row & 7)) << 4;
        gload16((const char*)(Qg + (size_t)row*512) + sw, sm + it*4096 + wid*1024);
        gload16((const char*)(Kg + (size_t)row*512) + sw, sm + 16384 + it*4096 + wid*1024);
    }
    {   // V transposed: Vt[c][j] — vectorized global loads, scalar LDS scatter
        int j = tid & 127, ch = tid >> 7;
        const u16* src = Vg + (size_t)j*512 + ch*32;
        uint4 a0 = *(const uint4*)(src);
        uint4 a1 = *(const uint4*)(src + 8);
        uint4 a2 = *(const uint4*)(src + 16);
        uint4 a3 = *(const uint4*)(src + 24);
        u32 w[16] = {a0.x,a0.y,a0.z,a0.w, a1.x,a1.y,a1.z,a1.w,
                     a2.x,a2.y,a2.z,a2.w, a3.x,a3.y,a3.z,a3.w};
        char* dst = sm + 34816 + ch*32*272 + j*2;
        #pragma unroll
        for (int cc = 0; cc < 32; ++cc) {
            u32 word = w[cc >> 1];
            u16 val = (cc & 1) ? (u16)(word >> 16) : (u16)(word & 0xffffu);
            *(u16*)(dst + cc*272) = val;
        }
    }
    __syncthreads();

    const int i0w = wid*32;
    f32x4 s[2][8];
    #pragma unroll
    for (int t = 0; t < 2; ++t)
        #pragma unroll
        for (int tj = 0; tj < 8; ++tj)
            s[t][tj] = f32x4{0.f,0.f,0.f,0.f};

    #pragma unroll
    for (int ks = 0; ks < 2; ++ks) {
        bf16x8 qf[2];
        #pragma unroll
        for (int t = 0; t < 2; ++t) {
            int ra = i0w + t*16 + li;
            qf[t] = *(const bf16x8*)(sm + ra*128 + ((ks*64 + lg*16) ^ ((ra & 7) << 4)));
        }
        #pragma unroll
        for (int tj = 0; tj < 8; ++tj) {
            int rb = tj*16 + li;
            bf16x8 kf = *(const bf16x8*)(sm + 16384 + rb*128 + ((ks*64 + lg*16) ^ ((rb & 7) << 4)));
            #pragma unroll
            for (int t = 0; t < 2; ++t)
                s[t][tj] = __builtin_amdgcn_mfma_f32_16x16x32_bf16(qf[t], kf, s[t][tj], 0, 0, 0);
        }
    }
    __syncthreads();   // Q/K LDS dead -> P overlay is now safe

    // wave-parallel softmax over j (scale 1/8 folded into exp arg)
    char* pb = sm + wid*8704;     // per-wave P [32 rows][272B stride]
    #pragma unroll
    for (int t = 0; t < 2; ++t) {
        #pragma unroll
        for (int r = 0; r < 4; ++r) {
            float mx = -1e30f;
            #pragma unroll
            for (int tj = 0; tj < 8; ++tj) mx = fmaxf(mx, s[t][tj][r]);
            #pragma unroll
            for (int off = 1; off < 16; off <<= 1) mx = fmaxf(mx, __shfl_xor(mx, off, 64));
            float p[8]; float sum = 0.f;
            #pragma unroll
            for (int tj = 0; tj < 8; ++tj) { p[tj] = __expf((s[t][tj][r] - mx)*0.125f); sum += p[tj]; }
            #pragma unroll
            for (int off = 1; off < 16; off <<= 1) sum += __shfl_xor(sum, off, 64);
            float inv = 1.0f / sum;
            int prow = t*16 + lg*4 + r;
            #pragma unroll
            for (int tj = 0; tj < 8; ++tj)
                *(u16*)(pb + prow*272 + (tj*16 + li)*2) = f2bf(p[tj]*inv);
        }
    }

    // O = P @ V
    f32x4 o[2][4];
    #pragma unroll
    for (int t = 0; t < 2; ++t)
        #pragma unroll
        for (int tc = 0; tc < 4; ++tc)
            o[t][tc] = f32x4{0.f,0.f,0.f,0.f};

    #pragma unroll
    for (int ks = 0; ks < 4; ++ks) {
        bf16x8 pf[2];
        #pragma unroll
        for (int t = 0; t < 2; ++t)
            pf[t] = *(const bf16x8*)(pb + (t*16 + li)*272 + (ks*64 + lg*16));
        #pragma unroll
        for (int tc = 0; tc < 4; ++tc) {
            bf16x8 vf = *(const bf16x8*)(sm + 34816 + (tc*16 + li)*272 + (ks*64 + lg*16));
            #pragma unroll
            for (int t = 0; t < 2; ++t)
                o[t][tc] = __builtin_amdgcn_mfma_f32_16x16x32_bf16(pf[t], vf, o[t][tc], 0, 0, 0);
        }
    }

    #pragma unroll
    for (int t = 0; t < 2; ++t)
        #pragma unroll
        for (int tc = 0; tc < 4; ++tc)
            #pragma unroll
            for (int r = 0; r < 4; ++r) {
                int irow = i0w + t*16 + lg*4 + r;
                int col = tc*16 + li;
                Og[(size_t)irow*512 + col] = f2bf(o[t][tc][r]);
            }
}

extern "C" void kernel_launch(void* const* d_in, const int* in_sizes, int n_in,
                              void* d_out, int out_size, void* d_ws, size_t ws_size,
                              hipStream_t stream){
    const float* x  = (const float*)d_in[0];
    const float* Wq = (const float*)d_in[1];
    const float* Wk = (const float*)d_in[2];
    const float* Wv = (const float*)d_in[3];
    const float* Wo = (const float*)d_in[4];
    const float* bo = (const float*)d_in[5];

    char* ws = (char*)d_ws;
    u16* Wcat = (u16*)ws;               // 1536*512 bf16
    u16* Wob  = Wcat + 1536*512;        // 512*512 bf16 ; weights end at 2097152 B

    // chunk over the 1024 attention rows: per chunk = CN*128*512*2 (xb) + 3x same (QKV planes)
    // CN floored at 128 so each chunk spans whole nb slices (OUTPROJ remap needs it)
    int CN = 1024;
    while (CN > 128 && (size_t)2097152 + (size_t)CN*524288 > ws_size) CN >>= 1;
    u16* xb   = (u16*)(ws + 2097152);      // also reused as O buffer by attn/outproj
    u16* QKV2 = xb + (size_t)CN*128*512;   // 3 planes [CN*128][512]
    int planesz = CN*128*512;

    // 128 KiB dynamic LDS for the 4-buffer GEMMs (idempotent; not a stream op, capture-safe)
    hipFuncSetAttribute((const void*)&k_gemm4<6, false>,
                        hipFuncAttributeMaxDynamicSharedMemorySize, 131072);
    hipFuncSetAttribute((const void*)&k_gemm4<2, true>,
                        hipFuncAttributeMaxDynamicSharedMemorySize, 131072);

    k_wconv<<<1024, 256, 0, stream>>>(Wq, Wk, Wv, Wo, Wcat, Wob);
    int nch = 1024 / CN;
    for (int ch = 0; ch < nch; ++ch) {
        int n0 = ch * CN;
        int nrow = (CN * 128) / 256;    // 256-row tiles in this chunk (multiple of 64)
        k_xconv<<<CN*32, 256, 0, stream>>>(x, xb, n0);
        k_gemm4<6, false><<<nrow*6, 512, 131072, stream>>>(xb, Wcat, QKV2, nullptr, 0, nrow, planesz);
        k_attn<<<dim3(8, CN), 256, 0, stream>>>(QKV2, QKV2 + planesz, QKV2 + 2*(size_t)planesz, xb);
        k_gemm4<2, true ><<<nrow*2, 512, 131072, stream>>>(xb, Wob, d_out, bo, n0, nrow, 0);
    }
}

// Round 13
// 602.975 us; speedup vs baseline: 1.2079x; 1.0189x over previous
//
#include <hip/hip_runtime.h>
#include <stdint.h>

// Axial attention (H axis), N=8 H=128 W=128 C=512, GROUPS=8, gp=64.
// Pipeline: wconv -> xconv(bf16+permute) -> QKV GEMM -> attn -> outproj.
// R13: both GEMMs use the R3 8-phase schedule (262us measured on QKV — session best),
// ported to plane outputs (R6) + outproj A-remap/dense-write (R8) + hoisted bases.
// k_gemm5: 256x256 block, 8 waves (2x4, wave-out 128x64), BK=64 tiles split in 2 half-K
// slabs; LDS 128KB = dbuf x {A0,B0,A1,B1} x 16KB ([256 rows][64B], slot-XOR swizzle,
// R6-verified 0 conflicts). Phases q0-q3: each stages one half-slab of tile t+1;
// VMC(4) BEFORE the pre-MFMA barrier at q1/q3 (retires exactly the 2 slabs needed next).
// ws: Q/K/V as separate [M][512] planes; O overwrites xb ([M][512]).

typedef __attribute__((ext_vector_type(4))) float f32x4;
typedef __attribute__((ext_vector_type(8))) short bf16x8;
typedef unsigned short u16;
typedef unsigned int u32;

#define CBAR() asm volatile("" ::: "memory")
#define SBAR() do { CBAR(); __builtin_amdgcn_s_barrier(); CBAR(); } while(0)
#define LGKM0() do { asm volatile("s_waitcnt lgkmcnt(0)" ::: "memory"); __builtin_amdgcn_sched_barrier(0); } while(0)
#define VMC(n) asm volatile("s_waitcnt vmcnt(" #n ")" ::: "memory")

static __device__ __forceinline__ u16 f2bf(float f){
    union { float f; u32 u; } v; v.f = f;
    u32 r = v.u + 0x7fffu + ((v.u >> 16) & 1u);   // RNE
    return (u16)(r >> 16);
}

static __device__ __forceinline__ void gload16(const void* g, void* l){
    __builtin_amdgcn_global_load_lds((const __attribute__((address_space(1))) void*)g,
                                     (__attribute__((address_space(3))) void*)l, 16, 0, 0);
}

// ---------------- weights fp32 -> bf16 ----------------
__global__ void k_wconv(const float* __restrict__ Wq, const float* __restrict__ Wk,
                        const float* __restrict__ Wv, const float* __restrict__ Wo,
                        u16* __restrict__ Wcat, u16* __restrict__ Wob){
    int e = (blockIdx.x * 256 + threadIdx.x) * 4;
    if (e < 1536*512) {
        int row = e >> 9, col = e & 511;
        const float* s = (row < 512) ? (Wq + row*512)
                        : (row < 1024 ? Wk + (row-512)*512 : Wv + (row-1024)*512);
        float4 v = *(const float4*)(s + col);
        ushort4 o = { f2bf(v.x), f2bf(v.y), f2bf(v.z), f2bf(v.w) };
        *(ushort4*)(Wcat + e) = o;
    } else {
        int e2 = e - 1536*512;
        float4 v = *(const float4*)(Wo + e2);
        ushort4 o = { f2bf(v.x), f2bf(v.y), f2bf(v.z), f2bf(v.w) };
        *(ushort4*)(Wob + e2) = o;
    }
}

// ---------------- x fp32 (N,H,W,C) -> xb bf16 [(n0+nl)*128+h][512] ----------------
__global__ void k_xconv(const float* __restrict__ x, u16* __restrict__ xb, int n0){
    int t = blockIdx.x * 256 + threadIdx.x;
    int ml = t >> 6;
    int c0 = (t & 63) << 3;
    int nl = ml >> 7, h = ml & 127;
    int n = n0 + nl, nb = n >> 7, w = n & 127;
    const float* src = x + (size_t)((nb*128 + h)*128 + w) * 512 + c0;
    float4 a = *(const float4*)(src);
    float4 b = *(const float4*)(src + 4);
    uint4 o;
    o.x = (u32)f2bf(a.x) | ((u32)f2bf(a.y) << 16);
    o.y = (u32)f2bf(a.z) | ((u32)f2bf(a.w) << 16);
    o.z = (u32)f2bf(b.x) | ((u32)f2bf(b.y) << 16);
    o.w = (u32)f2bf(b.z) | ((u32)f2bf(b.w) << 16);
    *(uint4*)(xb + (size_t)ml*512 + c0) = o;
}

// ---------------- 256x256 GEMM, R3 8-phase schedule: C = A[Mx512] * B^T ----------------
// LDS: buf{0,1} x slab{A0,B0,A1,B1} x 16KB; slab = [256 rows][64B] (BK=32 half-tile).
// Swizzle: LDS 16B-slot q of row r holds global chunk q^((r>>1)&3); read slot lg^((r>>1)&3).
// K-tile t (BK=64), phases:
//  q0: rd A0(mf0-3)+B0; stage next-A0; bar; lgkm0; 16 MFMA; bar
//  q1: rd A0(mf4-7);    stage next-B0; VMC(4) [retires cur A1,B1]; bar; lgkm0; MFMA; bar
//  q2: rd A1(mf0-3)+B1; stage next-A1; bar; lgkm0; MFMA; bar
//  q3: rd A1(mf4-7);    stage next-B1; VMC(4) [retires next A0,B0]; bar; lgkm0; MFMA; bar
// OUTPROJ: A row remap (nbL,h-pair)x w; dense NHWC writes (R8).
template<int NCOL, bool OUTPROJ>
__global__ __launch_bounds__(512, 2) void k_gemm5(const u16* __restrict__ A, const u16* __restrict__ B,
                                                  void* __restrict__ Cout, const float* __restrict__ bias,
                                                  int n0, int nrow, int planesz){
    extern __shared__ char smc[];
    const int tid = threadIdx.x;
    const int wid = tid >> 6, lane = tid & 63, lg = lane >> 4, li = lane & 15;
    const int wm = wid >> 2, wn = wid & 3;           // 2 x 4 wave grid, wave out 128x64
    const int bid = blockIdx.x;
    const int xcd = bid & 7, l = bid >> 3;
    const int row_tile = xcd * (nrow >> 3) + l / NCOL;
    const int col_tile = l % NCOL;
    const int m0 = row_tile * 256, nn0 = col_tile * 256;
    const int nbL = row_tile >> 6, h0 = (row_tile & 63) * 2;   // OUTPROJ geometry

    // hoisted per-lane stage bases (slot-XOR pre-swizzled source)
    const char* baseA[2]; const char* baseB[2]; int dstR[2];
    #pragma unroll
    for (int i = 0; i < 2; ++i) {
        int R = wid*32 + i*16;
        int r = R + (lane >> 2);
        int cq = (lane & 3) ^ ((r >> 1) & 3);
        long arow;
        if (OUTPROJ) arow = ((long)nbL*128 + (r & 127))*128 + h0 + (r >> 7);
        else         arow = m0 + r;
        baseA[i] = (const char*)(A + (size_t)arow*512) + cq*16;
        baseB[i] = (const char*)(B + (size_t)(nn0 + r)*512) + cq*16;
        dstR[i] = R;
    }
    // slab s in buffer bn: A-half h at bn + (h?2:0)*16384, B-half h at bn + (h?3:1)*16384
    auto stA = [&](char* bufb, int h, int koff){   // koff = byte offset of K-window
        char* sl = bufb + (h ? 2 : 0)*16384;
        #pragma unroll
        for (int i = 0; i < 2; ++i) gload16(baseA[i] + koff, sl + dstR[i]*64);
    };
    auto stB = [&](char* bufb, int h, int koff){
        char* sl = bufb + (h ? 3 : 1)*16384;
        #pragma unroll
        for (int i = 0; i < 2; ++i) gload16(baseB[i] + koff, sl + dstR[i]*64);
    };

    f32x4 acc[8][4];
    #pragma unroll
    for (int i = 0; i < 8; ++i)
        #pragma unroll
        for (int j = 0; j < 4; ++j)
            acc[i][j] = f32x4{0.f, 0.f, 0.f, 0.f};

    // prologue: tile 0 (A0,B0,A1,B1) into buf0; retire A0,B0
    stA(smc, 0, 0);
    stB(smc, 0, 0);
    stA(smc, 1, 64);
    stB(smc, 1, 64);
    VMC(4);
    SBAR();

    const int nT = 8;   // K = 512, BK = 64
    int cur = 0;
    bf16x8 af[4], bfr[4];

    #define RD_A(koff16, fbase) \
        _Pragma("unroll") \
        for (int f = 0; f < 4; ++f) { \
            int r = wm*128 + (fbase + f)*16 + li; \
            af[f] = *(const bf16x8*)(bc + (koff16)*16384 + r*64 + (((lg ^ (r >> 1)) & 3) << 4)); \
        }
    #define RD_B(koff16) \
        _Pragma("unroll") \
        for (int f = 0; f < 4; ++f) { \
            int r = wn*64 + f*16 + li; \
            bfr[f] = *(const bf16x8*)(bc + (koff16)*16384 + r*64 + (((lg ^ (r >> 1)) & 3) << 4)); \
        }
    #define MFMA16(abase) \
        __builtin_amdgcn_s_setprio(1); \
        _Pragma("unroll") \
        for (int fi = 0; fi < 4; ++fi) \
            _Pragma("unroll") \
            for (int fj = 0; fj < 4; ++fj) \
                acc[abase + fi][fj] = __builtin_amdgcn_mfma_f32_16x16x32_bf16(af[fi], bfr[fj], acc[abase + fi][fj], 0, 0, 0); \
        __builtin_amdgcn_s_setprio(0);

    for (int t = 0; t < nT; ++t) {
        const bool pf = (t + 1 < nT);
        char* bc = smc + cur*65536;
        char* bn = smc + (cur^1)*65536;
        const int kb = (t + 1) * 128;      // byte offset of next tile's K-window

        // ---- q0: A0 mf0-3 + B0
        RD_A(0, 0); RD_B(1);
        if (pf) stA(bn, 0, kb);
        SBAR(); LGKM0();
        MFMA16(0);
        SBAR();

        // ---- q1: A0 mf4-7 (B in regs)
        RD_A(0, 4);
        if (pf) stB(bn, 0, kb);
        if (pf) { VMC(4); } else { VMC(0); }   // retire cur A1,B1
        SBAR(); LGKM0();
        MFMA16(4);
        SBAR();

        // ---- q2: A1 mf0-3 + B1
        RD_A(2, 0); RD_B(3);
        if (pf) stA(bn, 1, kb + 64);
        SBAR(); LGKM0();
        MFMA16(0);
        SBAR();

        // ---- q3: A1 mf4-7
        RD_A(2, 4);
        if (pf) stB(bn, 1, kb + 64);
        if (pf) { VMC(4); }                    // retire next A0,B0
        SBAR(); LGKM0();
        MFMA16(4);
        SBAR();

        cur ^= 1;
    }
    #undef RD_A
    #undef RD_B
    #undef MFMA16

    // epilogue
    if (!OUTPROJ) {
        u16* Cp = (u16*)Cout + (size_t)(nn0 >> 9) * planesz;
        const int cb = (nn0 & 511) + wn*64;
        #pragma unroll
        for (int mf = 0; mf < 8; ++mf)
            #pragma unroll
            for (int nf = 0; nf < 4; ++nf)
                #pragma unroll
                for (int r = 0; r < 4; ++r) {
                    int row = m0 + wm*128 + mf*16 + lg*4 + r;
                    int col = cb + nf*16 + li;
                    Cp[(size_t)row*512 + col] = f2bf(acc[mf][nf][r]);
                }
    } else {
        float* C = (float*)Cout;
        const int nbG = (n0 >> 7) + nbL;
        #pragma unroll
        for (int mf = 0; mf < 8; ++mf)
            #pragma unroll
            for (int nf = 0; nf < 4; ++nf)
                #pragma unroll
                for (int r = 0; r < 4; ++r) {
                    int rho = wm*128 + mf*16 + lg*4 + r;
                    int w = rho & 127, hh = rho >> 7;
                    int col = nn0 + wn*64 + nf*16 + li;
                    size_t orow = (size_t)(nbG*128 + h0 + hh)*128 + w;
                    C[orow*512 + col] = acc[mf][nf][r] + bias[col];
                }
    }
}

// ---------------- attention: one block per (n_local, group), 4 waves x 32 rows ----------------
__global__ __launch_bounds__(256, 3) void k_attn(const u16* __restrict__ Qpl, const u16* __restrict__ Kpl,
                                                 const u16* __restrict__ Vpl, u16* __restrict__ Ob){
    // LDS: [0,16K) Qs swz, [16K,32K) Ks swz; P overlays [0,34816) after S-phase;
    //      Vt [34816, 34816+17408): [c=64][stride 272B] bf16
    __shared__ char sm[52224];
    const int g = blockIdx.x;
    const int nl = blockIdx.y;
    const int tid = threadIdx.x;
    const int wid = tid >> 6, lane = tid & 63, lg = lane >> 4, li = lane & 15;

    const u16* Qg = Qpl + (size_t)nl*128*512 + g*64;
    const u16* Kg = Kpl + (size_t)nl*128*512 + g*64;
    const u16* Vg = Vpl + (size_t)nl*128*512 + g*64;
    u16*       Og = Ob  + (size_t)nl*128*512 + g*64;

    #pragma unroll
    for (int it = 0; it < 4; ++it) {
        int gi = it*256 + tid;
        int row = gi >> 3, gs = gi & 7;
        int sw = (gs ^ (row & 7)) << 4;
        gload16((const char*)(Qg + (size_t)row*512) + sw, sm + it*4096 + wid*1024);
        gload16((const char*)(Kg + (size_t)row*512) + sw, sm + 16384 + it*4096 + wid*1024);
    }
    {   // V transposed: Vt[c][j] — vectorized global loads, scalar LDS scatter
        int j = tid & 127, ch = tid >> 7;
        const u16* src = Vg + (size_t)j*512 + ch*32;
        uint4 a0 = *(const uint4*)(src);
        uint4 a1 = *(const uint4*)(src + 8);
        uint4 a2 = *(const uint4*)(src + 16);
        uint4 a3 = *(const uint4*)(src + 24);
        u32 w[16] = {a0.x,a0.y,a0.z,a0.w, a1.x,a1.y,a1.z,a1.w,
                     a2.x,a2.y,a2.z,a2.w, a3.x,a3.y,a3.z,a3.w};
        char* dst = sm + 34816 + ch*32*272 + j*2;
        #pragma unroll
        for (int cc = 0; cc < 32; ++cc) {
            u32 word = w[cc >> 1];
            u16 val = (cc & 1) ? (u16)(word >> 16) : (u16)(word & 0xffffu);
            *(u16*)(dst + cc*272) = val;
        }
    }
    __syncthreads();

    const int i0w = wid*32;
    f32x4 s[2][8];
    #pragma unroll
    for (int t = 0; t < 2; ++t)
        #pragma unroll
        for (int tj = 0; tj < 8; ++tj)
            s[t][tj] = f32x4{0.f,0.f,0.f,0.f};

    #pragma unroll
    for (int ks = 0; ks < 2; ++ks) {
        bf16x8 qf[2];
        #pragma unroll
        for (int t = 0; t < 2; ++t) {
            int ra = i0w + t*16 + li;
            qf[t] = *(const bf16x8*)(sm + ra*128 + ((ks*64 + lg*16) ^ ((ra & 7) << 4)));
        }
        #pragma unroll
        for (int tj = 0; tj < 8; ++tj) {
            int rb = tj*16 + li;
            bf16x8 kf = *(const bf16x8*)(sm + 16384 + rb*128 + ((ks*64 + lg*16) ^ ((rb & 7) << 4)));
            #pragma unroll
            for (int t = 0; t < 2; ++t)
                s[t][tj] = __builtin_amdgcn_mfma_f32_16x16x32_bf16(qf[t], kf, s[t][tj], 0, 0, 0);
        }
    }
    __syncthreads();   // Q/K LDS dead -> P overlay is now safe

    // wave-parallel softmax over j (scale 1/8 folded into exp arg)
    char* pb = sm + wid*8704;     // per-wave P [32 rows][272B stride]
    #pragma unroll
    for (int t = 0; t < 2; ++t) {
        #pragma unroll
        for (int r = 0; r < 4; ++r) {
            float mx = -1e30f;
            #pragma unroll
            for (int tj = 0; tj < 8; ++tj) mx = fmaxf(mx, s[t][tj][r]);
            #pragma unroll
            for (int off = 1; off < 16; off <<= 1) mx = fmaxf(mx, __shfl_xor(mx, off, 64));
            float p[8]; float sum = 0.f;
            #pragma unroll
            for (int tj = 0; tj < 8; ++tj) { p[tj] = __expf((s[t][tj][r] - mx)*0.125f); sum += p[tj]; }
            #pragma unroll
            for (int off = 1; off < 16; off <<= 1) sum += __shfl_xor(sum, off, 64);
            float inv = 1.0f / sum;
            int prow = t*16 + lg*4 + r;
            #pragma unroll
            for (int tj = 0; tj < 8; ++tj)
                *(u16*)(pb + prow*272 + (tj*16 + li)*2) = f2bf(p[tj]*inv);
        }
    }

    // O = P @ V
    f32x4 o[2][4];
    #pragma unroll
    for (int t = 0; t < 2; ++t)
        #pragma unroll
        for (int tc = 0; tc < 4; ++tc)
            o[t][tc] = f32x4{0.f,0.f,0.f,0.f};

    #pragma unroll
    for (int ks = 0; ks < 4; ++ks) {
        bf16x8 pf[2];
        #pragma unroll
        for (int t = 0; t < 2; ++t)
            pf[t] = *(const bf16x8*)(pb + (t*16 + li)*272 + (ks*64 + lg*16));
        #pragma unroll
        for (int tc = 0; tc < 4; ++tc) {
            bf16x8 vf = *(const bf16x8*)(sm + 34816 + (tc*16 + li)*272 + (ks*64 + lg*16));
            #pragma unroll
            for (int t = 0; t < 2; ++t)
                o[t][tc] = __builtin_amdgcn_mfma_f32_16x16x32_bf16(pf[t], vf, o[t][tc], 0, 0, 0);
        }
    }

    #pragma unroll
    for (int t = 0; t < 2; ++t)
        #pragma unroll
        for (int tc = 0; tc < 4; ++tc)
            #pragma unroll
            for (int r = 0; r < 4; ++r) {
                int irow = i0w + t*16 + lg*4 + r;
                int col = tc*16 + li;
                Og[(size_t)irow*512 + col] = f2bf(o[t][tc][r]);
            }
}

extern "C" void kernel_launch(void* const* d_in, const int* in_sizes, int n_in,
                              void* d_out, int out_size, void* d_ws, size_t ws_size,
                              hipStream_t stream){
    const float* x  = (const float*)d_in[0];
    const float* Wq = (const float*)d_in[1];
    const float* Wk = (const float*)d_in[2];
    const float* Wv = (const float*)d_in[3];
    const float* Wo = (const float*)d_in[4];
    const float* bo = (const float*)d_in[5];

    char* ws = (char*)d_ws;
    u16* Wcat = (u16*)ws;               // 1536*512 bf16
    u16* Wob  = Wcat + 1536*512;        // 512*512 bf16 ; weights end at 2097152 B

    // chunk over the 1024 attention rows: per chunk = CN*128*512*2 (xb) + 3x same (QKV planes)
    // CN floored at 128 so each chunk spans whole nb slices (OUTPROJ remap needs it)
    int CN = 1024;
    while (CN > 128 && (size_t)2097152 + (size_t)CN*524288 > ws_size) CN >>= 1;
    u16* xb   = (u16*)(ws + 2097152);      // also reused as O buffer by attn/outproj
    u16* QKV2 = xb + (size_t)CN*128*512;   // 3 planes [CN*128][512]
    int planesz = CN*128*512;

    // 128 KiB dynamic LDS for the 8-phase GEMMs (idempotent; not a stream op, capture-safe)
    hipFuncSetAttribute((const void*)&k_gemm5<6, false>,
                        hipFuncAttributeMaxDynamicSharedMemorySize, 131072);
    hipFuncSetAttribute((const void*)&k_gemm5<2, true>,
                        hipFuncAttributeMaxDynamicSharedMemorySize, 131072);

    k_wconv<<<1024, 256, 0, stream>>>(Wq, Wk, Wv, Wo, Wcat, Wob);
    int nch = 1024 / CN;
    for (int ch = 0; ch < nch; ++ch) {
        int n0 = ch * CN;
        int nrow = (CN * 128) / 256;    // 256-row tiles in this chunk (multiple of 64)
        k_xconv<<<CN*32, 256, 0, stream>>>(x, xb, n0);
        k_gemm5<6, false><<<nrow*6, 512, 131072, stream>>>(xb, Wcat, QKV2, nullptr, 0, nrow, planesz);
        k_attn<<<dim3(8, CN), 256, 0, stream>>>(QKV2, QKV2 + planesz, QKV2 + 2*(size_t)planesz, xb);
        k_gemm5<2, true ><<<nrow*2, 512, 131072, stream>>>(xb, Wob, d_out, bo, n0, nrow, 0);
    }
}